// Round 1
// baseline (229.513 us; speedup 1.0000x reference)
//
#include <hip/hip_runtime.h>

typedef __attribute__((ext_vector_type(8))) short short8v;
typedef __attribute__((ext_vector_type(4))) float f32x4;

#define N_EDGES 1000000
#define NROWS   (N_EDGES * 3)
#define NTILES  (NROWS / 16)   // 187500 exactly

__device__ __forceinline__ unsigned short f2bf(float f) {
    unsigned u = __builtin_bit_cast(unsigned, f);
    u += 0x7fffu + ((u >> 16) & 1u);           // round-to-nearest-even
    return (unsigned short)(u >> 16);
}

// Build combined 64x32 bf16 matrix Mc in workspace:
//   rows 0..31  : 0.5*M1 + 0.25*M2   (multiplies a = W .* x_src)
//   rows 32..63 : -0.5*M1 + 0.25*M2  (multiplies b = W .* x_dst)
__global__ void build_mc(const float* __restrict__ M1, const float* __restrict__ M2,
                         unsigned short* __restrict__ mc) {
    int i = blockIdx.x * blockDim.x + threadIdx.x;
    if (i >= 64 * 32) return;
    int k = i >> 5;
    int f = i & 31;
    float v;
    if (k < 32) v =  0.5f * M1[k * 32 + f]        + 0.25f * M2[k * 32 + f];
    else        v = -0.5f * M1[(k - 32) * 32 + f] + 0.25f * M2[(k - 32) * 32 + f];
    mc[i] = f2bf(v);
}

__global__ __launch_bounds__(256) void n2e_main(
    const float* __restrict__ xn,
    const int*   __restrict__ src_idx,
    const int*   __restrict__ dst_idx,
    const float* __restrict__ W,
    const unsigned short* __restrict__ mc,
    float* __restrict__ out)
{
    const int lane = threadIdx.x & 63;
    const int wid  = threadIdx.x >> 6;
    const int col  = lane & 15;        // A row / D col / B col
    const int kg   = lane >> 4;        // 0..3
    const int kk   = kg << 3;          // k-offset of this lane's 8 elements

    // B fragments: B[chunk][ftile], lane holds B[k=(lane>>4)*8+i][col]
    short8v B00, B01, B10, B11;
    #pragma unroll
    for (int i = 0; i < 8; ++i) {
        int k0 = (kk + i) * 32;            // chunk 0 rows 0..31
        int k1 = (32 + kk + i) * 32;       // chunk 1 rows 32..63
        B00[i] = (short)mc[k0 + col];
        B01[i] = (short)mc[k0 + 16 + col];
        B10[i] = (short)mc[k1 + col];
        B11[i] = (short)mc[k1 + 16 + col];
    }

    for (int tile = blockIdx.x * 4 + wid; tile < NTILES; tile += gridDim.x * 4) {
        const int r0  = tile << 4;
        const int row = r0 + col;                 // global edge-row (e*3+d)
        const unsigned e = (unsigned)row / 3u;
        const int d = row - (int)e * 3;
        const int s = src_idx[e];
        const int t = dst_idx[e];

        const float* wp = W  + (size_t)e * 32 + kk;
        const float* sp = xn + ((size_t)s * 3 + d) * 32 + kk;
        const float* tp = xn + ((size_t)t * 3 + d) * 32 + kk;

        float4 w0 = *(const float4*)wp;
        float4 w1 = *(const float4*)(wp + 4);
        float4 s0 = *(const float4*)sp;
        float4 s1 = *(const float4*)(sp + 4);
        float4 t0 = *(const float4*)tp;
        float4 t1 = *(const float4*)(tp + 4);

        short8v fa, fb;
        fa[0] = (short)f2bf(w0.x * s0.x);
        fa[1] = (short)f2bf(w0.y * s0.y);
        fa[2] = (short)f2bf(w0.z * s0.z);
        fa[3] = (short)f2bf(w0.w * s0.w);
        fa[4] = (short)f2bf(w1.x * s1.x);
        fa[5] = (short)f2bf(w1.y * s1.y);
        fa[6] = (short)f2bf(w1.z * s1.z);
        fa[7] = (short)f2bf(w1.w * s1.w);
        fb[0] = (short)f2bf(w0.x * t0.x);
        fb[1] = (short)f2bf(w0.y * t0.y);
        fb[2] = (short)f2bf(w0.z * t0.z);
        fb[3] = (short)f2bf(w0.w * t0.w);
        fb[4] = (short)f2bf(w1.x * t1.x);
        fb[5] = (short)f2bf(w1.y * t1.y);
        fb[6] = (short)f2bf(w1.z * t1.z);
        fb[7] = (short)f2bf(w1.w * t1.w);

        f32x4 acc0 = {0.f, 0.f, 0.f, 0.f};
        f32x4 acc1 = {0.f, 0.f, 0.f, 0.f};
        acc0 = __builtin_amdgcn_mfma_f32_16x16x32_bf16(fa, B00, acc0, 0, 0, 0);
        acc0 = __builtin_amdgcn_mfma_f32_16x16x32_bf16(fb, B10, acc0, 0, 0, 0);
        acc1 = __builtin_amdgcn_mfma_f32_16x16x32_bf16(fa, B01, acc1, 0, 0, 0);
        acc1 = __builtin_amdgcn_mfma_f32_16x16x32_bf16(fb, B11, acc1, 0, 0, 0);

        // D: col = lane&15, row = r0 + kg*4 + i
        float* op = out + (size_t)(r0 + (kg << 2)) * 32 + col;
        #pragma unroll
        for (int i = 0; i < 4; ++i) {
            op[(size_t)i * 32]      = acc0[i];
            op[(size_t)i * 32 + 16] = acc1[i];
        }
    }
}

extern "C" void kernel_launch(void* const* d_in, const int* in_sizes, int n_in,
                              void* d_out, int out_size, void* d_ws, size_t ws_size,
                              hipStream_t stream) {
    const float* xn  = (const float*)d_in[0];
    const int*   xs  = (const int*)  d_in[1];
    const int*   xd  = (const int*)  d_in[2];
    const float* W   = (const float*)d_in[3];
    const float* M1  = (const float*)d_in[4];
    const float* M2  = (const float*)d_in[5];
    float* out = (float*)d_out;
    unsigned short* mc = (unsigned short*)d_ws;

    hipLaunchKernelGGL(build_mc, dim3(8), dim3(256), 0, stream, M1, M2, mc);
    hipLaunchKernelGGL(n2e_main, dim3(2048), dim3(256), 0, stream,
                       xn, xs, xd, W, mc, out);
}